// Round 16
// baseline (109.950 us; speedup 1.0000x reference)
//
#include <hip/hip_runtime.h>
#include <hip/hip_bf16.h>

typedef __hip_bfloat16 bf16;
typedef __attribute__((ext_vector_type(8))) short short8;
typedef __attribute__((ext_vector_type(4))) float f32x4;

#define SBAR() asm volatile("s_barrier" ::: "memory")
#define VMCNT8() asm volatile("s_waitcnt vmcnt(8)" ::: "memory")
#define VMCNT4() asm volatile("s_waitcnt vmcnt(4)" ::: "memory")
#define VMCNT0() asm volatile("s_waitcnt vmcnt(0)" ::: "memory")

__device__ __forceinline__ void gload_lds16(const bf16* g, bf16* l) {
  __builtin_amdgcn_global_load_lds(
      (const __attribute__((address_space(1))) unsigned int*)g,
      (__attribute__((address_space(3))) unsigned int*)l, 16, 0, 0);
}

// ---- BK=32 staging: one 128x32 K-tile (ld=1024) into an 8KB LDS slot,
// 256 threads x 2 insts. Conflict-free swizzle: phys chunk (t&3) holds global
// chunk g = (t&3) ^ ((row>>1)&3)  [row = p*64 + (t>>2); (row>>1)&3 = (t>>3)&3].
// Read-side inverse in lds_frag32 gives 2-way bank aliasing (free, m136).
__device__ __forceinline__ void stage32(const bf16* gbase, bf16* slot, int t) {
  const int g = ((t & 3) ^ ((t >> 3) & 3)) << 3;
  const int r = t >> 2;
  gload_lds16(gbase + (long)r * 1024 + g, slot + t * 8);
  gload_lds16(gbase + (long)(r + 64) * 1024 + g, slot + 2048 + t * 8);
}

// Logical (row, c16 0..3) of a [128][32] slot.
__device__ __forceinline__ short8 lds_frag32(const bf16* slot, int row, int c16) {
  return *(const short8*)(slot + row * 32 + ((c16 ^ ((row >> 1) & 3)) << 3));
}

// ---- BK=64 staging (prep2 only, proven).
__device__ __forceinline__ void stage_tile128_t256(const bf16* gbase, bf16* slot,
                                                   int t) {
#pragma unroll
  for (int p = 0; p < 4; ++p) {
    const int r = p * 32 + (t >> 3);
    const int c = ((t & 7) ^ (r & 7)) << 3;
    gload_lds16(gbase + (long)r * 1024 + c, slot + p * 2048 + t * 8);
  }
}
__device__ __forceinline__ short8 lds_frag(const bf16* slot, int row, int c16) {
  return *(const short8*)(slot + row * 64 + ((c16 ^ (row & 7)) << 3));
}

// ======== 128x128-tile, BK=32, 256-thr, 32KiB LDS, double-buffered counted
// vmcnt. __launch_bounds__(256,4) -> 4 blocks/CU (1024 slots).
// MODE 0: gv — id<512: G = BT(xb,Mp); id>=512: V'^T = BT(Wp, xb_b). bf16 out.
// MODE 1: sc — causal tiles, exp epilogue + part_l. bf16 out.
// MODE 2: pv — NT=(bm+1)*4, linv-scaled fp32 out.
template <int MODE>
__global__ __launch_bounds__(256, 4) void gemm128(
    const bf16* __restrict__ xb, const bf16* __restrict__ Mp,
    const bf16* __restrict__ Wp, bf16* __restrict__ G, bf16* __restrict__ VT,
    const bf16* __restrict__ Pin, bf16* __restrict__ Pout,
    float* __restrict__ part_l, float* __restrict__ Out) {
  __shared__ bf16 smem[16384];  // 32 KiB: A[2] + B[2] slots of 128x32
  const int id = blockIdx.x;
  const int t = threadIdx.x;
  const int lane = t & 63;
  const int wid = t >> 6;
  const int wr = (wid >> 1) * 64;
  const int wc = (wid & 1) * 64;
  const int lr = lane & 15;
  const int c16 = lane >> 4;
  const long SS = 1024L * 1024;

  const bf16 *Ag, *Bg;
  int arow, bcol, NT = 32, bz = 0, bm = 0, bn = 0;
  if (MODE == 0) {
    if (id < 512) {
      bm = (id & 7) + 8 * ((id >> 3) & 7);  // XCD-affine
      bn = id >> 6;
      arow = bm * 128;
      bcol = bn * 128;
      Ag = xb + (long)arow * 1024;
      Bg = Mp + (long)bcol * 1024;
    } else {
      const int v = id - 512;
      bz = v & 7;  // one batch per XCD
      const int gs = (v >> 3) & 7;
      const int ss = v >> 6;
      arow = gs * 128;
      bcol = ss * 128;
      Ag = Wp + (long)arow * 1024;
      Bg = xb + (long)bz * SS + (long)bcol * 1024;
    }
  } else if (MODE == 1) {
    bz = id & 7;
    int rr = id >> 3;  // triangular
    while (rr >= bm + 1) { rr -= bm + 1; ++bm; }
    bn = rr;
    arow = bm * 128;
    bcol = bn * 128;
    Ag = G + (long)bz * SS + (long)arow * 1024;
    Bg = xb + (long)bz * SS + (long)bcol * 1024;
  } else {
    bz = id & 7;
    const int w = id >> 3;
    bm = w & 7;
    bn = w >> 3;
    NT = (bm + 1) * 4;  // causal K-limit, BK=32
    arow = bm * 128;
    bcol = bn * 128;
    Ag = Pin + (long)bz * SS + (long)arow * 1024;
    Bg = VT + (long)bz * SS + (long)bcol * 1024;
  }

  bf16* sA = smem;         // 2 slots of 4096 elems
  bf16* sB = smem + 8192;  // 2 slots of 4096 elems

  // prologue: tiles 0 and 1 (NT >= 4 always)
  stage32(Ag, sA, t);
  stage32(Bg, sB, t);
  stage32(Ag + 32, sA + 4096, t);
  stage32(Bg + 32, sB + 4096, t);
  VMCNT4();  // tile 0 landed; tile 1's 4 loads may stay in flight
  SBAR();

  f32x4 acc[4][4] = {};
  for (int tt = 0; tt < NT; ++tt) {
    const int cur = tt & 1;
    const bf16* As = sA + cur * 4096;
    const bf16* Bs = sB + cur * 4096;
    short8 a[4], b[4];
#pragma unroll
    for (int m = 0; m < 4; ++m)
      a[m] = lds_frag32(As, wr + m * 16 + lr, c16);
#pragma unroll
    for (int n = 0; n < 4; ++n)
      b[n] = lds_frag32(Bs, wc + n * 16 + lr, c16);
#pragma unroll
    for (int m = 0; m < 4; ++m)
#pragma unroll
      for (int n = 0; n < 4; ++n)
        acc[m][n] = __builtin_amdgcn_mfma_f32_16x16x32_bf16(
            a[m], b[n], acc[m][n], 0, 0, 0);
    SBAR();  // all waves' reads of slot cur complete (lgkm before MFMA)
    if (tt + 2 < NT) {
      stage32(Ag + (tt + 2) * 32, sA + cur * 4096, t);
      stage32(Bg + (tt + 2) * 32, sB + cur * 4096, t);
      VMCNT4();  // tile tt+1 landed; tt+2 stays in flight
    } else if (tt + 1 < NT) {
      VMCNT0();
    }
    SBAR();
  }

  const int r0 = (lane >> 4) * 4;
  if (MODE == 0) {
    bf16* C = (id < 512) ? G : (VT + (long)bz * SS);
#pragma unroll
    for (int m = 0; m < 4; ++m)
#pragma unroll
      for (int n = 0; n < 4; ++n)
#pragma unroll
        for (int r = 0; r < 4; ++r)
          C[(long)(arow + wr + m * 16 + r0 + r) * 1024 + bcol + wc + n * 16 + lr] =
              __float2bfloat16(acc[m][n][r]);
  } else if (MODE == 1) {
    // exp + causal mask + store + deterministic per-row partial sums
    bf16* C = Pout + (long)bz * SS;
    float rsum[4][4];
#pragma unroll
    for (int m = 0; m < 4; ++m)
#pragma unroll
      for (int r = 0; r < 4; ++r) rsum[m][r] = 0.f;
#pragma unroll
    for (int m = 0; m < 4; ++m)
#pragma unroll
      for (int n = 0; n < 4; ++n)
#pragma unroll
        for (int r = 0; r < 4; ++r) {
          const int row = arow + wr + m * 16 + r0 + r;
          const int col = bcol + wc + n * 16 + lr;
          const float e = (col <= row) ? __expf(acc[m][n][r] * 0.03125f) : 0.f;
          C[(long)row * 1024 + col] = __float2bfloat16(e);
          rsum[m][r] += e;
        }
#pragma unroll
    for (int m = 0; m < 4; ++m)
#pragma unroll
      for (int r = 0; r < 4; ++r) {
#pragma unroll
        for (int o = 1; o < 16; o <<= 1)
          rsum[m][r] += __shfl_xor(rsum[m][r], o, 64);
      }
    float* wsum = (float*)smem;  // LDS free after final SBAR
    if (lr == 0) {
#pragma unroll
      for (int m = 0; m < 4; ++m)
#pragma unroll
        for (int r = 0; r < 4; ++r)
          wsum[(wid & 1) * 128 + wr + m * 16 + (lane >> 4) * 4 + r] = rsum[m][r];
    }
    __syncthreads();
    if (t < 128)
      part_l[(((long)bz * 8 + bm) * 8 + bn) * 128 + t] = wsum[t] + wsum[128 + t];
  } else {
    float* linv = (float*)smem;  // LDS free after final SBAR
    if (t < 128) {
      float l = 0.f;
      for (int j = 0; j <= bm; ++j)
        l += part_l[(((long)bz * 8 + bm) * 8 + j) * 128 + t];
      linv[t] = 1.f / l;
    }
    __syncthreads();
    float* C = Out + (long)bz * SS;
#pragma unroll
    for (int m = 0; m < 4; ++m)
#pragma unroll
      for (int r = 0; r < 4; ++r) {
        const int rl = wr + m * 16 + r0 + r;
        const float s = linv[rl];
#pragma unroll
        for (int n = 0; n < 4; ++n)
          C[(long)(arow + rl) * 1024 + bcol + wc + n * 16 + lr] =
              acc[m][n][r] * s;
      }
  }
}

// ---------------- prep2: full-K small GEMMs (blocks 0-127, BK=64) overlapped
// with x fp32->bf16 conversion (blocks 128-4223).
__global__ __launch_bounds__(256, 2) void prep2(
    const bf16* __restrict__ wkT, const bf16* __restrict__ wqT,
    const bf16* __restrict__ wo, const bf16* __restrict__ wvT,
    bf16* __restrict__ Mp, bf16* __restrict__ Wp, const float* __restrict__ x,
    bf16* __restrict__ xb) {
  __shared__ bf16 smem[32768];
  const int bid = blockIdx.x;
  const int t = threadIdx.x;

  if (bid >= 128) {  // x conversion
    const long i = (long)(bid - 128) * 2048 + t * 8;
    const float4 a = *(const float4*)&x[i];
    const float4 b = *(const float4*)&x[i + 4];
    const float va[8] = {a.x, a.y, a.z, a.w, b.x, b.y, b.z, b.w};
    union { bf16 h; short s; } u;
    short8 o;
#pragma unroll
    for (int j = 0; j < 8; ++j) { u.h = __float2bfloat16(va[j]); o[j] = u.s; }
    *(short8*)&xb[i] = o;
    return;
  }

  const int mat = bid >> 6;
  const int tile = bid & 63;
  const int bm = tile >> 3, bn = tile & 7;
  const bf16* A = (mat == 0) ? wkT : wo;
  const bf16* B = (mat == 0) ? wqT : wvT;
  bf16* C = (mat == 0) ? Mp : Wp;

  const int lane = t & 63;
  const int wid = t >> 6;
  const int wr = (wid >> 1) * 64;
  const int wc = (wid & 1) * 64;
  const int lr = lane & 15;
  const int c16 = lane >> 4;
  const int arow = bm * 128;
  const int brow = bn * 128;
  const bf16* Ag = A + (long)arow * 1024;
  const bf16* Bg = B + (long)brow * 1024;
  bf16* sA = smem;
  bf16* sB = smem + 16384;

  stage_tile128_t256(Ag, sA, t);
  stage_tile128_t256(Bg, sB, t);
  stage_tile128_t256(Ag + 64, sA + 8192, t);
  stage_tile128_t256(Bg + 64, sB + 8192, t);
  VMCNT8();
  SBAR();

  f32x4 acc[4][4] = {};
  for (int tt = 0; tt < 16; ++tt) {
    const int cur = tt & 1;
    const bf16* As = sA + cur * 8192;
    const bf16* Bs = sB + cur * 8192;
    short8 a[4][2], b[4][2];
#pragma unroll
    for (int m = 0; m < 4; ++m)
#pragma unroll
      for (int ks = 0; ks < 2; ++ks)
        a[m][ks] = lds_frag(As, wr + m * 16 + lr, c16 + ks * 4);
#pragma unroll
    for (int n = 0; n < 4; ++n)
#pragma unroll
      for (int ks = 0; ks < 2; ++ks)
        b[n][ks] = lds_frag(Bs, wc + n * 16 + lr, c16 + ks * 4);
#pragma unroll
    for (int m = 0; m < 4; ++m)
#pragma unroll
      for (int n = 0; n < 4; ++n)
#pragma unroll
        for (int ks = 0; ks < 2; ++ks)
          acc[m][n] = __builtin_amdgcn_mfma_f32_16x16x32_bf16(
              a[m][ks], b[n][ks], acc[m][n], 0, 0, 0);
    SBAR();
    if (tt + 2 < 16) {
      stage_tile128_t256(Ag + (tt + 2) * 64, sA + cur * 8192, t);
      stage_tile128_t256(Bg + (tt + 2) * 64, sB + cur * 8192, t);
      VMCNT8();
    } else if (tt + 1 < 16) {
      VMCNT0();
    }
    SBAR();
  }

#pragma unroll
  for (int m = 0; m < 4; ++m)
#pragma unroll
    for (int n = 0; n < 4; ++n)
#pragma unroll
      for (int r = 0; r < 4; ++r) {
        const int row = arow + wr + m * 16 + (lane >> 4) * 4 + r;
        const int col = brow + wc + n * 16 + lr;
        C[(long)row * 1024 + col] = __float2bfloat16(acc[m][n][r]);
      }
}

// fp32 -> bf16 weights: wq, wk, wv transposed (64x64 LDS tiles); wo plain.
__global__ __launch_bounds__(256) void f2bw(
    const float* __restrict__ wq, const float* __restrict__ wk,
    const float* __restrict__ wv, const float* __restrict__ wo,
    bf16* __restrict__ wqTb, bf16* __restrict__ wkTb,
    bf16* __restrict__ wvTb, bf16* __restrict__ wob) {
  __shared__ float T[64][65];
  const int bid = blockIdx.x;
  const int t = threadIdx.x;
  union { bf16 h; short s; } u;

  if (bid < 768) {
    const int mat = bid >> 8;
    const int tile = bid & 255;
    const int er = tile >> 4, dc = tile & 15;
    const float* src = ((mat == 0) ? wq : (mat == 1) ? wk : wv);
    bf16* dstb = ((mat == 0) ? wqTb : (mat == 1) ? wkTb : wvTb);
    const int r = t >> 2, c = (t & 3) * 16;
    const float* s0 = src + (long)(er * 64 + r) * 1024 + dc * 64 + c;
#pragma unroll
    for (int j = 0; j < 4; ++j) {
      const float4 v = *(const float4*)(s0 + j * 4);
      T[r][c + j * 4 + 0] = v.x;
      T[r][c + j * 4 + 1] = v.y;
      T[r][c + j * 4 + 2] = v.z;
      T[r][c + j * 4 + 3] = v.w;
    }
    __syncthreads();
    const int d = t >> 2, ec = (t & 3) * 16;
    bf16* dst = dstb + (long)(dc * 64 + d) * 1024 + er * 64 + ec;
#pragma unroll
    for (int half = 0; half < 2; ++half) {
      short8 o;
#pragma unroll
      for (int j = 0; j < 8; ++j) {
        u.h = __float2bfloat16(T[ec + half * 8 + j][d]);
        o[j] = u.s;
      }
      *(short8*)(dst + half * 8) = o;
    }
    return;
  }
  const long i = (long)(bid - 768) * 2048 + t * 8;
  const float4 a = *(const float4*)&wo[i];
  const float4 b = *(const float4*)&wo[i + 4];
  const float va[8] = {a.x, a.y, a.z, a.w, b.x, b.y, b.z, b.w};
  short8 o;
#pragma unroll
  for (int j = 0; j < 8; ++j) { u.h = __float2bfloat16(va[j]); o[j] = u.s; }
  *(short8*)&wob[i] = o;
}

extern "C" void kernel_launch(void* const* d_in, const int* in_sizes, int n_in,
                              void* d_out, int out_size, void* d_ws, size_t ws_size,
                              hipStream_t stream) {
  (void)in_sizes; (void)n_in; (void)out_size; (void)ws_size;
  const float* x  = (const float*)d_in[0];
  const float* wq = (const float*)d_in[1];
  const float* wk = (const float*)d_in[2];
  const float* wv = (const float*)d_in[3];
  const float* wo = (const float*)d_in[4];
  float* out = (float*)d_out;
  bf16* ws = (bf16*)d_ws;

  const long SB = 8192L * 1024;
  const long SW = 1024L * 1024;

  bf16* xb   = ws;                    // [8][s][d]
  bf16* wqTb = ws + SB;               // wq^T [d][e]
  bf16* wkTb = ws + SB + SW;          // wk^T [d][e]
  bf16* wvTb = ws + SB + 2 * SW;      // wv^T [d][e]
  bf16* wob  = ws + SB + 3 * SW;      // wo   [g][e]
  bf16* Mp   = ws + SB + 4 * SW;      // M' = wq^T wk
  bf16* Wp   = ws + SB + 5 * SW;      // W' = wo wv
  bf16* G    = ws + SB + 6 * SW;      // [8192][1024]
  bf16* VT   = G + SB;                // V'^T [8][g][s]
  bf16* P    = VT + SB;               // unnormalized P~
  float* part_l = (float*)(P + SB);   // [8][8][8][128] row partial sums

  f2bw<<<dim3(1280), dim3(256), 0, stream>>>(wq, wk, wv, wo, wqTb, wkTb, wvTb, wob);
  prep2<<<dim3(4224), dim3(256), 0, stream>>>(wkTb, wqTb, wob, wvTb, Mp, Wp, x, xb);
  // G and V'^T: 1024 blocks at 4/CU = 1 exact round
  gemm128<0><<<dim3(1024), dim3(256), 0, stream>>>(xb, Mp, Wp, G, VT,
                                                   nullptr, nullptr, nullptr, nullptr);
  // scores + exp + mask + partial sums: 288 causal blocks
  gemm128<1><<<dim3(288), dim3(256), 0, stream>>>(xb, nullptr, nullptr, G, nullptr,
                                                  nullptr, P, part_l, nullptr);
  // out = (P~ @ V') / l: 512 blocks, causal K-limit
  gemm128<2><<<dim3(512), dim3(256), 0, stream>>>(nullptr, nullptr, nullptr, nullptr,
                                                  VT, P, nullptr, part_l, out);
}

// Round 17
// 98.670 us; speedup vs baseline: 1.1143x; 1.1143x over previous
//
#include <hip/hip_runtime.h>
#include <hip/hip_bf16.h>

typedef __hip_bfloat16 bf16;
typedef __attribute__((ext_vector_type(8))) short short8;
typedef __attribute__((ext_vector_type(4))) float f32x4;

#define SBAR() asm volatile("s_barrier" ::: "memory")
#define VMCNT8() asm volatile("s_waitcnt vmcnt(8)" ::: "memory")
#define VMCNT0() asm volatile("s_waitcnt vmcnt(0)" ::: "memory")

__device__ __forceinline__ void gload_lds16(const bf16* g, bf16* l) {
  __builtin_amdgcn_global_load_lds(
      (const __attribute__((address_space(1))) unsigned int*)g,
      (__attribute__((address_space(3))) unsigned int*)l, 16, 0, 0);
}

// Stage one 128x64 K-tile (row-major, ld=1024) into a linear 16KB LDS slot,
// 256 threads (4 passes of 32 rows). Source col XOR-swizzled (rule 21).
__device__ __forceinline__ void stage_tile128_t256(const bf16* gbase, bf16* slot,
                                                   int t) {
#pragma unroll
  for (int p = 0; p < 4; ++p) {
    const int r = p * 32 + (t >> 3);
    const int c = ((t & 7) ^ (r & 7)) << 3;
    gload_lds16(gbase + (long)r * 1024 + c, slot + p * 2048 + t * 8);
  }
}

// Swizzled fragment read: logical (row, 16B-chunk c16) of a [128][64] slot.
__device__ __forceinline__ short8 lds_frag(const bf16* slot, int row, int c16) {
  return *(const short8*)(slot + row * 64 + ((c16 ^ (row & 7)) << 3));
}

// ======== 128x128-tile, BK=64, 256-thr, 64KiB, double-buffered counted-vmcnt
// K-loop (round-15 proven, 2 blocks/CU).
// MODE 0: G = BT(xb, Mp), 512 blocks (1 exact round), XCD-affine. bf16 out.
// MODE 1: merged V'+sc, 800 blocks — id<512: V'^T = BT(Wp, xb_b) (plain bf16);
//         id>=512: causal score tiles with exp epilogue + part_l.
// MODE 2: pv — NT=(bm+1)*2, linv-scaled fp32 out. 512 blocks.
template <int MODE>
__global__ __launch_bounds__(256, 2) void gemm128(
    const bf16* __restrict__ xb, const bf16* __restrict__ Mp,
    const bf16* __restrict__ Wp, bf16* __restrict__ G, bf16* __restrict__ VT,
    const bf16* __restrict__ Pin, bf16* __restrict__ Pout,
    float* __restrict__ part_l, float* __restrict__ Out) {
  __shared__ bf16 smem[32768];  // 64 KiB: A[2] + B[2] slots of 128x64
  const int id = blockIdx.x;
  const int t = threadIdx.x;
  const int lane = t & 63;
  const int wid = t >> 6;
  const int wr = (wid >> 1) * 64;
  const int wc = (wid & 1) * 64;
  const int lr = lane & 15;
  const int c16 = lane >> 4;
  const long SS = 1024L * 1024;

  const bf16 *Ag, *Bg;
  int arow, bcol, NT = 16, bz = 0, bm = 0, bn = 0;
  bool isV = false;
  if (MODE == 0) {
    // G: bm 0..63 (XCD-affine: same-XCD blocks share 8 A-panels), bn 0..7
    bm = (id & 7) + 8 * ((id >> 3) & 7);
    bn = id >> 6;
    arow = bm * 128;
    bcol = bn * 128;
    Ag = xb + (long)arow * 1024;
    Bg = Mp + (long)bcol * 1024;
  } else if (MODE == 1) {
    if (id < 512) {
      isV = true;
      bz = id & 7;  // one batch per XCD
      const int gs = (id >> 3) & 7;
      const int ss = id >> 6;
      arow = gs * 128;
      bcol = ss * 128;
      Ag = Wp + (long)arow * 1024;
      Bg = xb + (long)bz * SS + (long)bcol * 1024;
    } else {
      const int v = id - 512;
      bz = v & 7;
      int rr = v >> 3;  // 0..35 triangular
      while (rr >= bm + 1) { rr -= bm + 1; ++bm; }
      bn = rr;  // bn <= bm
      arow = bm * 128;
      bcol = bn * 128;
      Ag = G + (long)bz * SS + (long)arow * 1024;
      Bg = xb + (long)bz * SS + (long)bcol * 1024;
    }
  } else {
    bz = id & 7;
    const int w = id >> 3;
    bm = w & 7;
    bn = w >> 3;
    NT = (bm + 1) * 2;  // causal K-limit
    arow = bm * 128;
    bcol = bn * 128;
    Ag = Pin + (long)bz * SS + (long)arow * 1024;
    Bg = VT + (long)bz * SS + (long)bcol * 1024;
  }

  bf16* sA = smem;
  bf16* sB = smem + 16384;

  // prologue: tiles 0 and 1 (NT >= 2 always)
  stage_tile128_t256(Ag, sA, t);
  stage_tile128_t256(Bg, sB, t);
  stage_tile128_t256(Ag + 64, sA + 8192, t);
  stage_tile128_t256(Bg + 64, sB + 8192, t);
  VMCNT8();  // tile 0 landed; tile 1's 8 loads may stay in flight
  SBAR();

  f32x4 acc[4][4] = {};
  for (int tt = 0; tt < NT; ++tt) {
    const int cur = tt & 1;
    const bf16* As = sA + cur * 8192;
    const bf16* Bs = sB + cur * 8192;
    short8 a[4][2], b[4][2];
#pragma unroll
    for (int m = 0; m < 4; ++m)
#pragma unroll
      for (int ks = 0; ks < 2; ++ks)
        a[m][ks] = lds_frag(As, wr + m * 16 + lr, c16 + ks * 4);
#pragma unroll
    for (int n = 0; n < 4; ++n)
#pragma unroll
      for (int ks = 0; ks < 2; ++ks)
        b[n][ks] = lds_frag(Bs, wc + n * 16 + lr, c16 + ks * 4);
#pragma unroll
    for (int m = 0; m < 4; ++m)
#pragma unroll
      for (int n = 0; n < 4; ++n)
#pragma unroll
        for (int ks = 0; ks < 2; ++ks)
          acc[m][n] = __builtin_amdgcn_mfma_f32_16x16x32_bf16(
              a[m][ks], b[n][ks], acc[m][n], 0, 0, 0);
    SBAR();  // all waves' reads of slot cur have completed (lgkm before MFMA)
    if (tt + 2 < NT) {
      stage_tile128_t256(Ag + (tt + 2) * 64, sA + cur * 8192, t);
      stage_tile128_t256(Bg + (tt + 2) * 64, sB + cur * 8192, t);
      VMCNT8();  // tile tt+1 landed; tt+2 stays in flight
    } else if (tt + 1 < NT) {
      VMCNT0();
    }
    SBAR();
  }

  const int r0 = (lane >> 4) * 4;
  if (MODE == 0) {
#pragma unroll
    for (int m = 0; m < 4; ++m)
#pragma unroll
      for (int n = 0; n < 4; ++n)
#pragma unroll
        for (int r = 0; r < 4; ++r)
          G[(long)(arow + wr + m * 16 + r0 + r) * 1024 + bcol + wc + n * 16 + lr] =
              __float2bfloat16(acc[m][n][r]);
  } else if (MODE == 1) {
    if (isV) {
      bf16* C = VT + (long)bz * SS;
#pragma unroll
      for (int m = 0; m < 4; ++m)
#pragma unroll
        for (int n = 0; n < 4; ++n)
#pragma unroll
          for (int r = 0; r < 4; ++r)
            C[(long)(arow + wr + m * 16 + r0 + r) * 1024 + bcol + wc + n * 16 + lr] =
                __float2bfloat16(acc[m][n][r]);
    } else {
      // exp + causal mask + store + deterministic per-row partial sums
      bf16* C = Pout + (long)bz * SS;
      float rsum[4][4];
#pragma unroll
      for (int m = 0; m < 4; ++m)
#pragma unroll
        for (int r = 0; r < 4; ++r) rsum[m][r] = 0.f;
#pragma unroll
      for (int m = 0; m < 4; ++m)
#pragma unroll
        for (int n = 0; n < 4; ++n)
#pragma unroll
          for (int r = 0; r < 4; ++r) {
            const int row = arow + wr + m * 16 + r0 + r;
            const int col = bcol + wc + n * 16 + lr;
            const float e = (col <= row) ? __expf(acc[m][n][r] * 0.03125f) : 0.f;
            C[(long)row * 1024 + col] = __float2bfloat16(e);
            rsum[m][r] += e;
          }
#pragma unroll
      for (int m = 0; m < 4; ++m)
#pragma unroll
        for (int r = 0; r < 4; ++r) {
#pragma unroll
          for (int o = 1; o < 16; o <<= 1)
            rsum[m][r] += __shfl_xor(rsum[m][r], o, 64);
        }
      float* wsum = (float*)smem;  // LDS free after final SBAR
      if (lr == 0) {
#pragma unroll
        for (int m = 0; m < 4; ++m)
#pragma unroll
          for (int r = 0; r < 4; ++r)
            wsum[(wid & 1) * 128 + wr + m * 16 + (lane >> 4) * 4 + r] = rsum[m][r];
      }
      __syncthreads();
      if (t < 128)
        part_l[(((long)bz * 8 + bm) * 8 + bn) * 128 + t] = wsum[t] + wsum[128 + t];
    }
  } else {
    float* linv = (float*)smem;  // LDS free after final SBAR
    if (t < 128) {
      float l = 0.f;
      for (int j = 0; j <= bm; ++j)
        l += part_l[(((long)bz * 8 + bm) * 8 + j) * 128 + t];
      linv[t] = 1.f / l;
    }
    __syncthreads();
    float* C = Out + (long)bz * SS;
#pragma unroll
    for (int m = 0; m < 4; ++m)
#pragma unroll
      for (int r = 0; r < 4; ++r) {
        const int rl = wr + m * 16 + r0 + r;
        const float s = linv[rl];
#pragma unroll
        for (int n = 0; n < 4; ++n)
          C[(long)(arow + rl) * 1024 + bcol + wc + n * 16 + lr] =
              acc[m][n][r] * s;
      }
  }
}

// ---------------- prep2: full-K small GEMMs (blocks 0-127) overlapped with
// x fp32->bf16 conversion (blocks 128-4223).
__global__ __launch_bounds__(256, 2) void prep2(
    const bf16* __restrict__ wkT, const bf16* __restrict__ wqT,
    const bf16* __restrict__ wo, const bf16* __restrict__ wvT,
    bf16* __restrict__ Mp, bf16* __restrict__ Wp, const float* __restrict__ x,
    bf16* __restrict__ xb) {
  __shared__ bf16 smem[32768];
  const int bid = blockIdx.x;
  const int t = threadIdx.x;

  if (bid >= 128) {  // x conversion
    const long i = (long)(bid - 128) * 2048 + t * 8;
    const float4 a = *(const float4*)&x[i];
    const float4 b = *(const float4*)&x[i + 4];
    const float va[8] = {a.x, a.y, a.z, a.w, b.x, b.y, b.z, b.w};
    union { bf16 h; short s; } u;
    short8 o;
#pragma unroll
    for (int j = 0; j < 8; ++j) { u.h = __float2bfloat16(va[j]); o[j] = u.s; }
    *(short8*)&xb[i] = o;
    return;
  }

  const int mat = bid >> 6;
  const int tile = bid & 63;
  const int bm = tile >> 3, bn = tile & 7;
  const bf16* A = (mat == 0) ? wkT : wo;
  const bf16* B = (mat == 0) ? wqT : wvT;
  bf16* C = (mat == 0) ? Mp : Wp;

  const int lane = t & 63;
  const int wid = t >> 6;
  const int wr = (wid >> 1) * 64;
  const int wc = (wid & 1) * 64;
  const int lr = lane & 15;
  const int c16 = lane >> 4;
  const int arow = bm * 128;
  const int brow = bn * 128;
  const bf16* Ag = A + (long)arow * 1024;
  const bf16* Bg = B + (long)brow * 1024;
  bf16* sA = smem;
  bf16* sB = smem + 16384;

  stage_tile128_t256(Ag, sA, t);
  stage_tile128_t256(Bg, sB, t);
  stage_tile128_t256(Ag + 64, sA + 8192, t);
  stage_tile128_t256(Bg + 64, sB + 8192, t);
  VMCNT8();
  SBAR();

  f32x4 acc[4][4] = {};
  for (int tt = 0; tt < 16; ++tt) {
    const int cur = tt & 1;
    const bf16* As = sA + cur * 8192;
    const bf16* Bs = sB + cur * 8192;
    short8 a[4][2], b[4][2];
#pragma unroll
    for (int m = 0; m < 4; ++m)
#pragma unroll
      for (int ks = 0; ks < 2; ++ks)
        a[m][ks] = lds_frag(As, wr + m * 16 + lr, c16 + ks * 4);
#pragma unroll
    for (int n = 0; n < 4; ++n)
#pragma unroll
      for (int ks = 0; ks < 2; ++ks)
        b[n][ks] = lds_frag(Bs, wc + n * 16 + lr, c16 + ks * 4);
#pragma unroll
    for (int m = 0; m < 4; ++m)
#pragma unroll
      for (int n = 0; n < 4; ++n)
#pragma unroll
        for (int ks = 0; ks < 2; ++ks)
          acc[m][n] = __builtin_amdgcn_mfma_f32_16x16x32_bf16(
              a[m][ks], b[n][ks], acc[m][n], 0, 0, 0);
    SBAR();
    if (tt + 2 < 16) {
      stage_tile128_t256(Ag + (tt + 2) * 64, sA + cur * 8192, t);
      stage_tile128_t256(Bg + (tt + 2) * 64, sB + cur * 8192, t);
      VMCNT8();
    } else if (tt + 1 < 16) {
      VMCNT0();
    }
    SBAR();
  }

#pragma unroll
  for (int m = 0; m < 4; ++m)
#pragma unroll
    for (int n = 0; n < 4; ++n)
#pragma unroll
      for (int r = 0; r < 4; ++r) {
        const int row = arow + wr + m * 16 + (lane >> 4) * 4 + r;
        const int col = brow + wc + n * 16 + lr;
        C[(long)row * 1024 + col] = __float2bfloat16(acc[m][n][r]);
      }
}

// fp32 -> bf16 weights: wq, wk, wv transposed (64x64 LDS tiles); wo plain.
__global__ __launch_bounds__(256) void f2bw(
    const float* __restrict__ wq, const float* __restrict__ wk,
    const float* __restrict__ wv, const float* __restrict__ wo,
    bf16* __restrict__ wqTb, bf16* __restrict__ wkTb,
    bf16* __restrict__ wvTb, bf16* __restrict__ wob) {
  __shared__ float T[64][65];
  const int bid = blockIdx.x;
  const int t = threadIdx.x;
  union { bf16 h; short s; } u;

  if (bid < 768) {
    const int mat = bid >> 8;
    const int tile = bid & 255;
    const int er = tile >> 4, dc = tile & 15;
    const float* src = ((mat == 0) ? wq : (mat == 1) ? wk : wv);
    bf16* dstb = ((mat == 0) ? wqTb : (mat == 1) ? wkTb : wvTb);
    const int r = t >> 2, c = (t & 3) * 16;
    const float* s0 = src + (long)(er * 64 + r) * 1024 + dc * 64 + c;
#pragma unroll
    for (int j = 0; j < 4; ++j) {
      const float4 v = *(const float4*)(s0 + j * 4);
      T[r][c + j * 4 + 0] = v.x;
      T[r][c + j * 4 + 1] = v.y;
      T[r][c + j * 4 + 2] = v.z;
      T[r][c + j * 4 + 3] = v.w;
    }
    __syncthreads();
    const int d = t >> 2, ec = (t & 3) * 16;
    bf16* dst = dstb + (long)(dc * 64 + d) * 1024 + er * 64 + ec;
#pragma unroll
    for (int half = 0; half < 2; ++half) {
      short8 o;
#pragma unroll
      for (int j = 0; j < 8; ++j) {
        u.h = __float2bfloat16(T[ec + half * 8 + j][d]);
        o[j] = u.s;
      }
      *(short8*)(dst + half * 8) = o;
    }
    return;
  }
  const long i = (long)(bid - 768) * 2048 + t * 8;
  const float4 a = *(const float4*)&wo[i];
  const float4 b = *(const float4*)&wo[i + 4];
  const float va[8] = {a.x, a.y, a.z, a.w, b.x, b.y, b.z, b.w};
  short8 o;
#pragma unroll
  for (int j = 0; j < 8; ++j) { u.h = __float2bfloat16(va[j]); o[j] = u.s; }
  *(short8*)&wob[i] = o;
}

extern "C" void kernel_launch(void* const* d_in, const int* in_sizes, int n_in,
                              void* d_out, int out_size, void* d_ws, size_t ws_size,
                              hipStream_t stream) {
  (void)in_sizes; (void)n_in; (void)out_size; (void)ws_size;
  const float* x  = (const float*)d_in[0];
  const float* wq = (const float*)d_in[1];
  const float* wk = (const float*)d_in[2];
  const float* wv = (const float*)d_in[3];
  const float* wo = (const float*)d_in[4];
  float* out = (float*)d_out;
  bf16* ws = (bf16*)d_ws;

  const long SB = 8192L * 1024;
  const long SW = 1024L * 1024;

  bf16* xb   = ws;                    // [8][s][d]
  bf16* wqTb = ws + SB;               // wq^T [d][e]
  bf16* wkTb = ws + SB + SW;          // wk^T [d][e]
  bf16* wvTb = ws + SB + 2 * SW;      // wv^T [d][e]
  bf16* wob  = ws + SB + 3 * SW;      // wo   [g][e]
  bf16* Mp   = ws + SB + 4 * SW;      // M' = wq^T wk
  bf16* Wp   = ws + SB + 5 * SW;      // W' = wo wv
  bf16* G    = ws + SB + 6 * SW;      // [8192][1024]
  bf16* VT   = G + SB;                // V'^T [8][g][s]
  bf16* P    = VT + SB;               // unnormalized P~
  float* part_l = (float*)(P + SB);   // [8][8][8][128] row partial sums

  f2bw<<<dim3(1280), dim3(256), 0, stream>>>(wq, wk, wv, wo, wqTb, wkTb, wvTb, wob);
  prep2<<<dim3(4224), dim3(256), 0, stream>>>(wkTb, wqTb, wob, wvTb, Mp, Wp, x, xb);
  // G = x M': 512 blocks = 1 exact round at 2/CU
  gemm128<0><<<dim3(512), dim3(256), 0, stream>>>(xb, Mp, Wp, G, VT,
                                                  nullptr, nullptr, nullptr, nullptr);
  // V'^T (512, independent of G) + causal scores (288, needs G): 800 blocks
  gemm128<1><<<dim3(800), dim3(256), 0, stream>>>(xb, Mp, Wp, G, VT,
                                                  nullptr, P, part_l, nullptr);
  // out = (P~ @ V') / l: 512 blocks, causal K-limit
  gemm128<2><<<dim3(512), dim3(256), 0, stream>>>(nullptr, nullptr, nullptr, nullptr,
                                                  VT, P, nullptr, part_l, out);
}